// Round 17
// baseline (1211.910 us; speedup 1.0000x reference)
//
#include <hip/hip_runtime.h>
#include <math.h>

#define FEATD 128
#define DIM 64
#define NB 256
#define SCB 256
#define KB 16      // attention partial blocks per graph
#define RNG 128    // nodes per CSR-fill bucket
#define NBUCKMAX 2048
#define CH1 8192   // edges per block, bin-scatter phase
#define DB 64      // degree buckets for load-balance permutation

typedef short bf16x8 __attribute__((ext_vector_type(8)));
typedef float f32x4 __attribute__((ext_vector_type(4)));

__device__ __forceinline__ float frcp_(float x){ return __builtin_amdgcn_rcpf(x); }
__device__ __forceinline__ float sigmoidf_(float x){ return frcp_(1.f+__expf(-x)); }
__device__ __forceinline__ float tanhf_(float x){ float e=__expf(2.f*x); return 1.f-2.f*frcp_(e+1.f); }

__device__ __forceinline__ unsigned short f2bf(float f){
  unsigned u = __float_as_uint(f);
  unsigned r = (u + 0x7FFFu + ((u>>16)&1u)) >> 16;
  return (unsigned short)r;
}
__device__ __forceinline__ float bf2f(unsigned short s){
  return __uint_as_float(((unsigned)s)<<16);
}

__device__ __forceinline__ int lower_bound_i(const int* __restrict__ a, int n, int key){
  int lo=0, hi=n;
  while(lo<hi){ int mid=(lo+hi)>>1; if(a[mid]<key) lo=mid+1; else hi=mid; }
  return lo;
}

// ======================= CSR setup =======================
__global__ void k_count(const int* __restrict__ col, int* __restrict__ deg, int E){
  int i=blockIdx.x*blockDim.x+threadIdx.x;
  if(i<E) atomicAdd(&deg[col[i]],1);
}

// --- multi-block exclusive scan; also computes dinv + degree histogram in the same pass ---
__global__ __launch_bounds__(256) void k_scan_part(const int* __restrict__ deg, int* __restrict__ part,
                                                   float* __restrict__ dinv, int* __restrict__ dhist, int n){
  __shared__ int s[256];
  __shared__ int lh[DB];
  int b=blockIdx.x;
  if(threadIdx.x<DB) lh[threadIdx.x]=0;
  __syncthreads();
  int chunk=(n+SCB-1)/SCB;
  int lo=b*chunk, hi=min(lo+chunk,n);
  int acc=0;
  for(int i=lo+threadIdx.x;i<hi;i+=256){
    int d=deg[i];
    acc+=d;
    dinv[i]=rsqrtf((float)(d+1)); // +1 self-loop
    atomicAdd(&lh[min(d,DB-1)],1);
  }
  s[threadIdx.x]=acc; __syncthreads();
  for(int off=128;off;off>>=1){
    if(threadIdx.x<off) s[threadIdx.x]+=s[threadIdx.x+off];
    __syncthreads();
  }
  if(threadIdx.x==0) part[b]=s[0];
  if(threadIdx.x<DB && lh[threadIdx.x]>0) atomicAdd(&dhist[threadIdx.x],lh[threadIdx.x]);
}

__global__ __launch_bounds__(256) void k_scan_mid(int* __restrict__ part, int* __restrict__ dhist){
  __shared__ int s[256];
  int t=threadIdx.x;
  s[t]=part[t]; __syncthreads();
  for(int off=1;off<256;off<<=1){
    int v=(t>=off)? s[t-off]:0;
    __syncthreads();
    s[t]+=v;
    __syncthreads();
  }
  part[t]=(t>0)? s[t-1]:0;  // exclusive
  if(t==0){  // serial exclusive scan of the 64-entry degree histogram
    int run=0;
    for(int i=0;i<DB;i++){ int v=dhist[i]; dhist[i]=run; run+=v; }
  }
}

// degree-balance permutation: perm[pos]=node, pos grouped by degree bucket
__global__ void k_dplace(const int* __restrict__ deg, int* __restrict__ dhist, int* __restrict__ perm, int n){
  int i=blockIdx.x*blockDim.x+threadIdx.x;
  if(i>=n) return;
  int b=min(deg[i],DB-1);
  int pos=atomicAdd(&dhist[b],1);
  perm[pos]=i;
}

// also fills gcur[b*32] = rp[b*RNG] (bucket cursors) on the fly
__global__ __launch_bounds__(256) void k_scan_out(const int* __restrict__ deg, const int* __restrict__ part,
                                                  int* __restrict__ rp, int* __restrict__ gcur, int n){
  __shared__ int s[256];
  int b=blockIdx.x, t=threadIdx.x;
  int chunk=(n+SCB-1)/SCB;
  int lo=b*chunk, hi=min(lo+chunk,n);
  int tchunk=(chunk+255)/256;
  int tlo=lo+t*tchunk, thi=min(tlo+tchunk,hi);
  int acc=0;
  for(int i=tlo;i<thi;i++) acc+=deg[i];
  s[t]=acc; __syncthreads();
  for(int off=1;off<256;off<<=1){
    int v=(t>=off)? s[t-off]:0;
    __syncthreads();
    s[t]+=v;
    __syncthreads();
  }
  int pre=part[b]+((t>0)? s[t-1]:0);
  for(int i=tlo;i<thi;i++){
    rp[i]=pre;
    if((i&(RNG-1))==0) gcur[(i>>7)*32]=pre;
    pre+=deg[i];
  }
  if(b==SCB-1 && t==0) rp[n]=part[b]+s[255];
}

// ======================= bucketed CSR fill =======================
__global__ __launch_bounds__(256) void k_binscat(const int* __restrict__ row, const int* __restrict__ col,
                       int* __restrict__ gcur, unsigned* __restrict__ tmp, int E, int nbuck){
  __shared__ int lcnt[NBUCKMAX];
  __shared__ int lcur[NBUCKMAX];
  int t=threadIdx.x;
  for(int i=t;i<nbuck;i+=256) lcnt[i]=0;
  __syncthreads();
  int lo=blockIdx.x*CH1, hi=min(lo+CH1,E);
  for(int i=lo+t;i<hi;i+=256) atomicAdd(&lcnt[col[i]>>7],1);
  __syncthreads();
  for(int i=t;i<nbuck;i+=256){
    int cnt=lcnt[i];
    lcur[i]=(cnt>0)? atomicAdd(&gcur[i*32],cnt):0;
  }
  __syncthreads();
  for(int i=lo+t;i<hi;i+=256){
    int c=col[i], r=row[i];
    int pos=atomicAdd(&lcur[c>>7],1);
    tmp[pos]=((unsigned)r<<7)|(unsigned)(c&127);
  }
}

__global__ __launch_bounds__(256) void k_place(const unsigned* __restrict__ tmp, const int* __restrict__ rp,
                      const float* __restrict__ dinv, int2* __restrict__ epack, int n, int nbuck){
  __shared__ int lfill[RNG];
  __shared__ int lrp[RNG];
  __shared__ float ldv[RNG];
  int b=blockIdx.x, t=threadIdx.x;
  int nbase=b*RNG;
  int nn=min(RNG,n-nbase);
  if(t<nn){ lfill[t]=0; lrp[t]=rp[nbase+t]; ldv[t]=dinv[nbase+t]; }
  __syncthreads();
  int lo=rp[nbase], hi=rp[min(nbase+RNG,n)];
  for(int j=lo+t;j<hi;j+=256){
    unsigned v=tmp[j];
    int cl=v&127;
    int r=(int)(v>>7);
    int pos=atomicAdd(&lfill[cl],1);
    epack[lrp[cl]+pos]=make_int2(r,__float_as_int(dinv[r]*ldv[cl]));
  }
}

// ======================= MFMA B-fragment prep =======================
// mfma_f32_16x16x32_bf16 fragments:
//   A: lane l holds row (l&15), k = s*32 + (l>>4)*8 + r   (r=0..7)
//   B: lane l holds col (l&15), k = s*32 + (l>>4)*8 + r
//   D: lane l holds col (l&15), row = (l>>4)*4 + reg
// Plain (t-major) frags: Bf[((t*S + s)*64 + lane)*8 + r] = W[k][c], t=c/16, S=K/32.
__global__ void k_prep_plain(const float* __restrict__ W, unsigned short* __restrict__ Bf, int K, int C){
  int i=blockIdx.x*blockDim.x+threadIdx.x;
  if(i>=K*C) return;
  int k=i/C, c=i%C;
  int t=c>>4, s=k>>5, lane=(c&15)|(((k>>3)&3)<<4), r=k&7;
  int S=K>>5;
  Bf[(((t*S)+s)*64+lane)*8+r]=f2bf(W[(size_t)k*C+c]);
}

// Assembled GRU weights, S-MAJOR frag order (f = s*16+t) so each 16KB quarter (one s) is contiguous.
// X=[m|h] (K=128), cols: [0,64)=r, [64,128)=z, [128,192)=in_, [192,256)=hn.
__global__ void k_prep_gru(const float* __restrict__ wih, const float* __restrict__ whh,
                           unsigned short* __restrict__ Bf){
  int i=blockIdx.x*blockDim.x+threadIdx.x;
  if(i>=128*256) return;
  int k=i>>8, c=i&255;
  float v;
  if(c<128){          // r,z
    v = (k<64) ? wih[c*64+k] : whh[c*64+(k-64)];
  } else if(c<192){   // in_
    v = (k<64) ? wih[c*64+k] : 0.f;
  } else {            // hn
    v = (k<64) ? 0.f : whh[(c-64)*64+(k-64)];
  }
  int t=c>>4, s=k>>5, lane=(c&15)|(((k>>3)&3)<<4), r=k&7;
  Bf[(((s*16)+t)*64+lane)*8+r]=f2bf(v);
}

// ======================= lin0: hb = bf16(relu(x @ W + b)), LDS-staged coalesced store ===================
__global__ __launch_bounds__(256) void k_lin0(const float* __restrict__ x, const unsigned short* __restrict__ Bf,
                      const float* __restrict__ bias,
                      unsigned short* __restrict__ hb, int ngrp){
  __shared__ __align__(16) unsigned short lt[4][16][72];
  int l=threadIdx.x&63, w=threadIdx.x>>6;
  int g=blockIdx.x*4+w;
  if(g>=ngrp) return;
  int row16=l&15, koff=(l>>4)*8, l16=l&15;
  f32x4 acc[4]={};
  const float* xr = x + (size_t)(g*16+row16)*128 + koff;
  #pragma unroll
  for(int s=0;s<4;s++){
    f32x4 a0=*(const f32x4*)(xr+s*32);
    f32x4 a1=*(const f32x4*)(xr+s*32+4);
    bf16x8 af;
    #pragma unroll
    for(int r=0;r<4;r++){ af[r]=(short)f2bf(a0[r]); af[4+r]=(short)f2bf(a1[r]); }
    #pragma unroll
    for(int t=0;t<4;t++){
      bf16x8 bf=*(const bf16x8*)(Bf+(((t*4)+s)*64+l)*8);
      acc[t]=__builtin_amdgcn_mfma_f32_16x16x32_bf16(af,bf,acc[t],0,0,0);
    }
  }
  #pragma unroll
  for(int t=0;t<4;t++){
    int c=t*16+l16;
    float b=bias[c];
    #pragma unroll
    for(int j=0;j<4;j++)
      lt[w][(l>>4)*4+j][c]=f2bf(fmaxf(acc[t][j]+b,0.f));
  }
  #pragma unroll
  for(int i=0;i<4;i++){
    int rl=i*4+(l>>4);
    uint2 v=*(const uint2*)&lt[w][rl][l16*4];
    ((uint2*)hb)[(((unsigned)(g*16+rl))<<4)+l16]=v;
  }
}

// ======================= fused aggregate + conv + GRU (round-13 config + degree-balanced perm) ===========
__global__ __launch_bounds__(256,4) void k_gruagg(
                     const unsigned short* __restrict__ hin, unsigned short* __restrict__ hout,
                     const int* __restrict__ rp, const int2* __restrict__ epack,
                     const float* __restrict__ dinv, const int* __restrict__ perm,
                     const unsigned short* __restrict__ Bcnv, const float* __restrict__ cb,
                     const unsigned short* __restrict__ Bgru,
                     const float* __restrict__ bih, const float* __restrict__ bhh,
                     float* __restrict__ h, int last, int ngrp, int n){
  __shared__ __align__(16) unsigned short Bs[8192];          // 16 KB: one s-quarter of Bgru
  __shared__ __align__(16) unsigned short tAH[4][2][16][72]; // [w][0]=agg/m tile, [w][1]=h tile
  int tid=threadIdx.x;
  int l=tid&63, w=tid>>6;
  int g=blockIdx.x*4+w;
  bool act = g<ngrp;
  int gc = act? g : (ngrp-1);
  int q=l>>4, l16=l&15;
  int row16=l&15, koff=(l>>4)*8;

  unsigned short (*tA)[72] = tAH[w][0];
  unsigned short (*tH)[72] = tAH[w][1];

  // conv B-frags into registers (issued early, resolve under gather)
  bf16x8 bc[8];
  #pragma unroll
  for(int f=0;f<8;f++) bc[f]=*(const bf16x8*)(Bcnv+((size_t)f*64+l)*8);

  // stage Bgru quarter s=0
  {
    const f32x4* gh=(const f32x4*)Bgru; f32x4* lh=(f32x4*)Bs;
    #pragma unroll
    for(int i=0;i<4;i++) lh[i*256+tid]=gh[i*256+tid];
  }

  // ---- gather: 4 rounds; quarter q owns node perm[gc*16+rr*4+q]; 8-wide main, 4/2/1 tails ----
  // perm is degree-sorted: the 4 nodes of a round have similar degree -> lockstep trips balanced.
  const uint2* h64=(const uint2*)hin;
  #pragma unroll
  for(int rr=0;rr<4;rr++){
    int node=perm[min(gc*16+rr*4+q, n-1)];
    float a0=0.f,a1=0.f,a2=0.f,a3=0.f, b0=0.f,b1=0.f,b2=0.f,b3=0.f;
    int s=rp[node], e=rp[node+1];
    uint2 selfp=h64[((unsigned)node<<4)+l16];
    int j=s;
    for(; j+7<e; j+=8){
      int2 e0=epack[j],   e1=epack[j+1], e2=epack[j+2], e3=epack[j+3];
      int2 e4=epack[j+4], e5=epack[j+5], e6=epack[j+6], e7=epack[j+7];
      uint2 p0=h64[((unsigned)e0.x<<4)+l16];
      uint2 p1=h64[((unsigned)e1.x<<4)+l16];
      uint2 p2=h64[((unsigned)e2.x<<4)+l16];
      uint2 p3=h64[((unsigned)e3.x<<4)+l16];
      uint2 p4=h64[((unsigned)e4.x<<4)+l16];
      uint2 p5=h64[((unsigned)e5.x<<4)+l16];
      uint2 p6=h64[((unsigned)e6.x<<4)+l16];
      uint2 p7=h64[((unsigned)e7.x<<4)+l16];
      float n0=__int_as_float(e0.y), n1=__int_as_float(e1.y);
      float n2=__int_as_float(e2.y), n3=__int_as_float(e3.y);
      float n4=__int_as_float(e4.y), n5=__int_as_float(e5.y);
      float n6=__int_as_float(e6.y), n7=__int_as_float(e7.y);
      a0+=n0*bf2f((unsigned short)p0.x); a1+=n0*bf2f((unsigned short)(p0.x>>16));
      a2+=n0*bf2f((unsigned short)p0.y); a3+=n0*bf2f((unsigned short)(p0.y>>16));
      b0+=n1*bf2f((unsigned short)p1.x); b1+=n1*bf2f((unsigned short)(p1.x>>16));
      b2+=n1*bf2f((unsigned short)p1.y); b3+=n1*bf2f((unsigned short)(p1.y>>16));
      a0+=n2*bf2f((unsigned short)p2.x); a1+=n2*bf2f((unsigned short)(p2.x>>16));
      a2+=n2*bf2f((unsigned short)p2.y); a3+=n2*bf2f((unsigned short)(p2.y>>16));
      b0+=n3*bf2f((unsigned short)p3.x); b1+=n3*bf2f((unsigned short)(p3.x>>16));
      b2+=n3*bf2f((unsigned short)p3.y); b3+=n3*bf2f((unsigned short)(p3.y>>16));
      a0+=n4*bf2f((unsigned short)p4.x); a1+=n4*bf2f((unsigned short)(p4.x>>16));
      a2+=n4*bf2f((unsigned short)p4.y); a3+=n4*bf2f((unsigned short)(p4.y>>16));
      b0+=n5*bf2f((unsigned short)p5.x); b1+=n5*bf2f((unsigned short)(p5.x>>16));
      b2+=n5*bf2f((unsigned short)p5.y); b3+=n5*bf2f((unsigned short)(p5.y>>16));
      a0+=n6*bf2f((unsigned short)p6.x); a1+=n6*bf2f((unsigned short)(p6.x>>16));
      a2+=n6*bf2f((unsigned short)p6.y); a3+=n6*bf2f((unsigned short)(p6.y>>16));
      b0+=n7*bf2f((unsigned short)p7.x); b1+=n7*bf2f((unsigned short)(p7.x>>16));
      b2+=n7*bf2f((unsigned short)p7.y); b3+=n7*bf2f((unsigned short)(p7.y>>16));
    }
    for(; j+3<e; j+=4){
      int2 e0=epack[j];
      int2 e1=epack[j+1];
      int2 e2=epack[j+2];
      int2 e3=epack[j+3];
      uint2 p0=h64[((unsigned)e0.x<<4)+l16];
      uint2 p1=h64[((unsigned)e1.x<<4)+l16];
      uint2 p2=h64[((unsigned)e2.x<<4)+l16];
      uint2 p3=h64[((unsigned)e3.x<<4)+l16];
      float n0=__int_as_float(e0.y), n1=__int_as_float(e1.y);
      float n2=__int_as_float(e2.y), n3=__int_as_float(e3.y);
      a0+=n0*bf2f((unsigned short)p0.x); a1+=n0*bf2f((unsigned short)(p0.x>>16));
      a2+=n0*bf2f((unsigned short)p0.y); a3+=n0*bf2f((unsigned short)(p0.y>>16));
      b0+=n1*bf2f((unsigned short)p1.x); b1+=n1*bf2f((unsigned short)(p1.x>>16));
      b2+=n1*bf2f((unsigned short)p1.y); b3+=n1*bf2f((unsigned short)(p1.y>>16));
      a0+=n2*bf2f((unsigned short)p2.x); a1+=n2*bf2f((unsigned short)(p2.x>>16));
      a2+=n2*bf2f((unsigned short)p2.y); a3+=n2*bf2f((unsigned short)(p2.y>>16));
      b0+=n3*bf2f((unsigned short)p3.x); b1+=n3*bf2f((unsigned short)(p3.x>>16));
      b2+=n3*bf2f((unsigned short)p3.y); b3+=n3*bf2f((unsigned short)(p3.y>>16));
    }
    for(; j+1<e; j+=2){
      int2 e0=epack[j];
      int2 e1=epack[j+1];
      uint2 p0=h64[((unsigned)e0.x<<4)+l16];
      uint2 p1=h64[((unsigned)e1.x<<4)+l16];
      float n0=__int_as_float(e0.y), n1=__int_as_float(e1.y);
      a0+=n0*bf2f((unsigned short)p0.x); a1+=n0*bf2f((unsigned short)(p0.x>>16));
      a2+=n0*bf2f((unsigned short)p0.y); a3+=n0*bf2f((unsigned short)(p0.y>>16));
      b0+=n1*bf2f((unsigned short)p1.x); b1+=n1*bf2f((unsigned short)(p1.x>>16));
      b2+=n1*bf2f((unsigned short)p1.y); b3+=n1*bf2f((unsigned short)(p1.y>>16));
    }
    if(j<e){
      int2 e0=epack[j];
      uint2 p0=h64[((unsigned)e0.x<<4)+l16];
      float n0=__int_as_float(e0.y);
      a0+=n0*bf2f((unsigned short)p0.x); a1+=n0*bf2f((unsigned short)(p0.x>>16));
      a2+=n0*bf2f((unsigned short)p0.y); a3+=n0*bf2f((unsigned short)(p0.y>>16));
    }
    float dv=dinv[node]; dv*=dv;
    a0+=b0+dv*bf2f((unsigned short)selfp.x);
    a1+=b1+dv*bf2f((unsigned short)(selfp.x>>16));
    a2+=b2+dv*bf2f((unsigned short)selfp.y);
    a3+=b3+dv*bf2f((unsigned short)(selfp.y>>16));
    int ri=rr*4+q;
    unsigned* tAp=(unsigned*)&tA[ri][l16*4];
    tAp[0]=(unsigned)f2bf(a0)|(((unsigned)f2bf(a1))<<16);
    tAp[1]=(unsigned)f2bf(a2)|(((unsigned)f2bf(a3))<<16);
    unsigned* tHp=(unsigned*)&tH[ri][l16*4];
    tHp[0]=selfp.x; tHp[1]=selfp.y;
  }

  // ---- conv mini-GEMM: m = relu(agg[16x64] @ Wc + cb); A-frags from tA (same wave) ----
  f32x4 accm[4]={};
  #pragma unroll
  for(int s=0;s<2;s++){
    bf16x8 af=*(const bf16x8*)&tA[row16][s*32+koff];
    #pragma unroll
    for(int t=0;t<4;t++)
      accm[t]=__builtin_amdgcn_mfma_f32_16x16x32_bf16(af,bc[t*2+s],accm[t],0,0,0);
  }
  // m -> tA (overwrite; same-wave lockstep safe)
  #pragma unroll
  for(int t=0;t<4;t++){
    int c=t*16+l16;
    float b=cb[c];
    #pragma unroll
    for(int j=0;j<4;j++)
      tA[(l>>4)*4+j][c]=f2bf(fmaxf(accm[t][j]+b,0.f));
  }

  // ---- GRU GEMM over 4 K-slices, Bs restaged per slice ----
  f32x4 acc[16]={};
  __syncthreads();   // Bs quarter 0 visible
  #pragma unroll
  for(int s=0;s<4;s++){
    if(s>0){
      __syncthreads();  // prior quarter reads done
      const f32x4* gh=(const f32x4*)(Bgru+(size_t)s*8192); f32x4* lh=(f32x4*)Bs;
      #pragma unroll
      for(int i=0;i<4;i++) lh[i*256+tid]=gh[i*256+tid];
      __syncthreads();  // quarter s visible
    }
    bf16x8 af;
    if(s<2) af=*(const bf16x8*)&tA[row16][s*32+koff];
    else    af=*(const bf16x8*)&tH[row16][(s-2)*32+koff];
    #pragma unroll
    for(int t=0;t<16;t++){
      bf16x8 bf=*(const bf16x8*)(Bs+((size_t)t*64+l)*8);
      acc[t]=__builtin_amdgcn_mfma_f32_16x16x32_bf16(af,bf,acc[t],0,0,0);
    }
  }

  if(!act) return;
  // ---- epilogue: gates in-register; hold from tH (read before overwrite) ----
  float hn[16];
  #pragma unroll
  for(int t=0;t<4;t++){
    int d=t*16+l16;
    float br =bih[d]    +bhh[d];
    float bz =bih[64+d] +bhh[64+d];
    float bni=bih[128+d];
    float bnh=bhh[128+d];
    #pragma unroll
    for(int j=0;j<4;j++){
      float r  = sigmoidf_(acc[t][j]   + br);
      float z  = sigmoidf_(acc[4+t][j] + bz);
      float nc = tanhf_(acc[8+t][j] + bni + r*(acc[12+t][j] + bnh));
      float hold=bf2f(tH[(l>>4)*4+j][d]);
      hn[t*4+j]=(1.f-z)*nc + z*hold;
    }
  }
  // stage hn (bf16) into tH, then per-row writeback to perm'd node rows (128B contiguous each)
  #pragma unroll
  for(int t=0;t<4;t++){
    int d=t*16+l16;
    #pragma unroll
    for(int j=0;j<4;j++)
      tH[(l>>4)*4+j][d]=f2bf(hn[t*4+j]);
  }
  #pragma unroll
  for(int i=0;i<4;i++){
    int rl=i*4+(l>>4);
    int node=perm[gc*16+rl];
    uint2 v=*(const uint2*)&tH[rl][l16*4];
    ((uint2*)hout)[(((unsigned)node<<4))+l16]=v;
  }
  if(last){
    // f32 feat via LDS transpose over the (now-free) tA+tH storage: float[16][68], 4352B <= 4608B
    float* ft=(float*)&tAH[w][0][0][0];
    #pragma unroll
    for(int t=0;t<4;t++){
      int d=t*16+l16;
      #pragma unroll
      for(int j=0;j<4;j++)
        ft[((l>>4)*4+j)*68+d]=hn[t*4+j];
    }
    #pragma unroll
    for(int i=0;i<4;i++){
      int rl=i*4+(l>>4);
      int node=perm[gc*16+rl];
      f32x4 v=*(const f32x4*)&ft[rl*68+l16*4];
      *(f32x4*)&h[(size_t)node*64+l16*4]=v;
    }
  }
}

// ======================= Set2Set: parallel attention partials =======================
__global__ __launch_bounds__(256) void k_attn_part(const unsigned short* __restrict__ hb, const int* __restrict__ batch,
                        const float* __restrict__ hl, float* __restrict__ apart, int n){
  int b=blockIdx.x/KB, kb=blockIdx.x%KB;
  int tid=threadIdx.x, lane=tid&63, w=tid>>6;
  __shared__ float qs[64];
  __shared__ float wm[4], wsm[4];
  __shared__ float wacc[4][64];
  if(tid<64) qs[tid]=hl[b*64+tid];
  int lo=lower_bound_i(batch,n,b), hi=lower_bound_i(batch,n,b+1);
  int cnt=hi-lo;
  int chunk=(cnt+KB-1)/KB;
  int slo=lo+kb*chunk, shi=min(slo+chunk,hi);
  __syncthreads();
  float q=qs[lane];
  float mw=-3.0e38f, sw=0.f, aw=0.f;
  for(int i=slo+w;i<shi;i+=4){
    float f=bf2f(hb[(size_t)i*64+lane]);
    float v=f*q;
    #pragma unroll
    for(int off=32;off;off>>=1) v+=__shfl_xor(v,off);
    if(v>mw){
      float sc=__expf(mw-v);
      sw=sw*sc+1.f;
      aw=aw*sc+f;
      mw=v;
    } else {
      float p=__expf(v-mw);
      sw+=p;
      aw+=p*f;
    }
  }
  if(lane==0){ wm[w]=mw; wsm[w]=sw; }
  wacc[w][lane]=aw;
  __syncthreads();
  if(w==0){
    float M=fmaxf(fmaxf(wm[0],wm[1]),fmaxf(wm[2],wm[3]));
    float S=0.f, A=0.f;
    #pragma unroll
    for(int k=0;k<4;k++){
      float sc=__expf(wm[k]-M);
      S+=wsm[k]*sc;
      A+=wacc[k][lane]*sc;
    }
    float* p=apart+(size_t)blockIdx.x*68;
    p[lane]=A;
    if(lane==0){ p[64]=M; p[65]=S; }
  }
}

// merge partials -> r_read (qstar[64:128]); optionally run next LSTM cell
__global__ __launch_bounds__(256) void k_merge_lstm(const float* __restrict__ apart,
                   float* __restrict__ qstar, float* __restrict__ hl, float* __restrict__ cl,
                   const float* __restrict__ wih, const float* __restrict__ whh,
                   const float* __restrict__ bih, const float* __restrict__ bhh,
                   int do_merge, int do_lstm){
  int b=blockIdx.x, tid=threadIdx.x;
  __shared__ float qs[128];
  __shared__ float gates[256];
  if(do_merge){
    if(tid<64){
      const float* p0=apart+(size_t)b*KB*68;
      float M=-3.0e38f;
      #pragma unroll
      for(int k=0;k<KB;k++) M=fmaxf(M,p0[k*68+64]);
      float S=0.f, A=0.f;
      #pragma unroll
      for(int k=0;k<KB;k++){
        float sc=__expf(p0[k*68+64]-M);
        S+=p0[k*68+65]*sc;
        A+=p0[k*68+tid]*sc;
      }
      float inv=(S>0.f)? 1.f/S:0.f;
      float r=A*inv;
      qs[64+tid]=r;
      qstar[b*128+64+tid]=r;
    }
  } else {
    if(tid<64) qs[64+tid]=qstar[b*128+64+tid];
  }
  if(tid<64) qs[tid]=hl[b*64+tid];   // q_t == previous LSTM hidden
  __syncthreads();
  if(!do_lstm) return;
  float acc=bih[tid]+bhh[tid];
  const float* wi=wih+(size_t)tid*128;
  #pragma unroll 8
  for(int k=0;k<128;k++) acc+=qs[k]*wi[k];
  const float* w2=whh+(size_t)tid*64;
  #pragma unroll 8
  for(int k=0;k<64;k++) acc+=qs[k]*w2[k];
  gates[tid]=acc;
  __syncthreads();
  if(tid<64){
    float i_=gates[tid], f_=gates[64+tid], g_=gates[128+tid], o_=gates[192+tid];
    float c=sigmoidf_(f_)*cl[b*64+tid]+sigmoidf_(i_)*tanhf(g_);
    float hn=sigmoidf_(o_)*tanhf(c);
    cl[b*64+tid]=c; hl[b*64+tid]=hn;
    qstar[b*128+tid]=hn;
  }
}

extern "C" void kernel_launch(void* const* d_in, const int* in_sizes, int n_in,
                              void* d_out, int out_size, void* d_ws, size_t ws_size,
                              hipStream_t stream){
  const float* x      =(const float*)d_in[0];
  const int*   ei     =(const int*)d_in[1];
  const int*   batch  =(const int*)d_in[2];
  const float* lin0_w =(const float*)d_in[3];
  const float* lin0_b =(const float*)d_in[4];
  const float* conv_w =(const float*)d_in[5];
  const float* conv_b =(const float*)d_in[6];
  const float* gwih   =(const float*)d_in[7];
  const float* gwhh   =(const float*)d_in[8];
  const float* gbih   =(const float*)d_in[9];
  const float* gbhh   =(const float*)d_in[10];
  const float* lwih   =(const float*)d_in[11];
  const float* lwhh   =(const float*)d_in[12];
  const float* lbih   =(const float*)d_in[13];
  const float* lbhh   =(const float*)d_in[14];

  int N = in_sizes[0]/FEATD;
  int E = in_sizes[1]/2;
  const int* row = ei;
  const int* col = ei + E;

  float* qstar = (float*)d_out;            // [256,128]
  float* h     = (float*)d_out + NB*2*DIM; // [N,64] 'feat' = f32 h (written by last k_gruagg)

  char* ws=(char*)d_ws;
  size_t off=0;
  auto alloc=[&](size_t bytes)->void*{ void* p=ws+off; off=(off+bytes+255)&~(size_t)255; return p; };
  int*   deg  =(int*)  alloc((size_t)N*4);
  float* dinv =(float*)alloc((size_t)N*4);
  int*   rp   =(int*)  alloc((size_t)(N+1)*4);
  int*   part =(int*)  alloc((size_t)SCB*4);
  int*   gcur =(int*)  alloc((size_t)NBUCKMAX*32*4);
  int*   dhist=(int*)  alloc((size_t)DB*4);
  int*   perm =(int*)  alloc((size_t)N*4);
  unsigned* tmp=(unsigned*)alloc((size_t)E*4);
  int2*  epack=(int2*) alloc((size_t)E*8);
  unsigned short* hb0  =(unsigned short*)alloc((size_t)N*64*2);
  unsigned short* hb1  =(unsigned short*)alloc((size_t)N*64*2);
  float* hl   =(float*)alloc((size_t)NB*DIM*4);
  float* cl   =(float*)alloc((size_t)NB*DIM*4);
  float* apart=(float*)alloc((size_t)NB*KB*68*4);
  unsigned short* Bgru =(unsigned short*)alloc(128*256*2);
  unsigned short* Blin =(unsigned short*)alloc(128*64*2);
  unsigned short* Bcnv =(unsigned short*)alloc(64*64*2);

  hipMemsetAsync(deg ,0,(size_t)N*4,stream);
  hipMemsetAsync(dhist,0,(size_t)DB*4,stream);
  hipMemsetAsync(hl  ,0,(size_t)NB*DIM*4,stream);
  hipMemsetAsync(cl  ,0,(size_t)NB*DIM*4,stream);
  hipMemsetAsync(qstar,0,(size_t)NB*2*DIM*4,stream);

  int nbuck=(N+RNG-1)/RNG;

  k_count<<<(E+255)/256,256,0,stream>>>(col,deg,E);
  k_scan_part<<<SCB,256,0,stream>>>(deg,part,dinv,dhist,N);
  k_scan_mid <<<1,256,0,stream>>>(part,dhist);
  k_dplace<<<(N+255)/256,256,0,stream>>>(deg,dhist,perm,N);
  k_scan_out <<<SCB,256,0,stream>>>(deg,part,rp,gcur,N);
  k_binscat<<<(E+CH1-1)/CH1,256,0,stream>>>(row,col,gcur,tmp,E,nbuck);
  k_place<<<nbuck,256,0,stream>>>(tmp,rp,dinv,epack,N,nbuck);

  k_prep_plain<<<(128*64+255)/256,256,0,stream>>>(lin0_w,Blin,128,64);
  k_prep_plain<<<(64*64+255)/256,256,0,stream>>>(conv_w,Bcnv,64,64);
  k_prep_gru  <<<(128*256+255)/256,256,0,stream>>>(gwih,gwhh,Bgru);

  int ngrp=(N+15)/16;
  int gb=(ngrp+3)/4;

  k_lin0<<<gb,256,0,stream>>>(x,Blin,lin0_b,hb0,ngrp);

  // h double-buffer: it0 hb0->hb1, it1 hb1->hb0, it2 hb0->hb1 (final in hb1)
  k_gruagg<<<gb,256,0,stream>>>(hb0,hb1,rp,epack,dinv,perm,Bcnv,conv_b,Bgru,gbih,gbhh,h,0,ngrp,N);
  k_gruagg<<<gb,256,0,stream>>>(hb1,hb0,rp,epack,dinv,perm,Bcnv,conv_b,Bgru,gbih,gbhh,h,0,ngrp,N);
  k_gruagg<<<gb,256,0,stream>>>(hb0,hb1,rp,epack,dinv,perm,Bcnv,conv_b,Bgru,gbih,gbhh,h,1,ngrp,N);

  // Set2Set: lstm0; [attn, merge+lstm] x2; attn; merge(final)
  k_merge_lstm<<<NB,256,0,stream>>>(apart,qstar,hl,cl,lwih,lwhh,lbih,lbhh,0,1);
  for(int st=0;st<3;st++){
    k_attn_part<<<NB*KB,256,0,stream>>>(hb1,batch,hl,apart,N);
    int do_lstm = (st<2)? 1:0;
    k_merge_lstm<<<NB,256,0,stream>>>(apart,qstar,hl,cl,lwih,lwhh,lbih,lbhh,1,do_lstm);
  }
}

// Round 18
// 537.851 us; speedup vs baseline: 2.2532x; 2.2532x over previous
//
#include <hip/hip_runtime.h>
#include <math.h>

#define FEATD 128
#define DIM 64
#define NB 256
#define SCB 256
#define KB 16      // attention partial blocks per graph
#define RNG 128    // nodes per CSR-fill bucket
#define NBUCKMAX 2048
#define CH1 8192   // edges per block, bin-scatter phase

typedef short bf16x8 __attribute__((ext_vector_type(8)));
typedef float f32x4 __attribute__((ext_vector_type(4)));

__device__ __forceinline__ float frcp_(float x){ return __builtin_amdgcn_rcpf(x); }
__device__ __forceinline__ float sigmoidf_(float x){ return frcp_(1.f+__expf(-x)); }
__device__ __forceinline__ float tanhf_(float x){ float e=__expf(2.f*x); return 1.f-2.f*frcp_(e+1.f); }

__device__ __forceinline__ unsigned short f2bf(float f){
  unsigned u = __float_as_uint(f);
  unsigned r = (u + 0x7FFFu + ((u>>16)&1u)) >> 16;
  return (unsigned short)r;
}
__device__ __forceinline__ float bf2f(unsigned short s){
  return __uint_as_float(((unsigned)s)<<16);
}

__device__ __forceinline__ int lower_bound_i(const int* __restrict__ a, int n, int key){
  int lo=0, hi=n;
  while(lo<hi){ int mid=(lo+hi)>>1; if(a[mid]<key) lo=mid+1; else hi=mid; }
  return lo;
}

// ======================= CSR setup =======================
__global__ void k_count(const int* __restrict__ col, int* __restrict__ deg, int E){
  int i=blockIdx.x*blockDim.x+threadIdx.x;
  if(i<E) atomicAdd(&deg[col[i]],1);
}

// --- multi-block exclusive scan; also computes dinv in the same deg pass ---
__global__ __launch_bounds__(256) void k_scan_part(const int* __restrict__ deg, int* __restrict__ part,
                                                   float* __restrict__ dinv, int n){
  __shared__ int s[256];
  int b=blockIdx.x;
  int chunk=(n+SCB-1)/SCB;
  int lo=b*chunk, hi=min(lo+chunk,n);
  int acc=0;
  for(int i=lo+threadIdx.x;i<hi;i+=256){
    int d=deg[i];
    acc+=d;
    dinv[i]=rsqrtf((float)(d+1)); // +1 self-loop
  }
  s[threadIdx.x]=acc; __syncthreads();
  for(int off=128;off;off>>=1){
    if(threadIdx.x<off) s[threadIdx.x]+=s[threadIdx.x+off];
    __syncthreads();
  }
  if(threadIdx.x==0) part[b]=s[0];
}

__global__ __launch_bounds__(256) void k_scan_mid(int* __restrict__ part){
  __shared__ int s[256];
  int t=threadIdx.x;
  s[t]=part[t]; __syncthreads();
  for(int off=1;off<256;off<<=1){
    int v=(t>=off)? s[t-off]:0;
    __syncthreads();
    s[t]+=v;
    __syncthreads();
  }
  part[t]=(t>0)? s[t-1]:0;  // exclusive
}

// also fills gcur[b*32] = rp[b*RNG] (bucket cursors) on the fly
__global__ __launch_bounds__(256) void k_scan_out(const int* __restrict__ deg, const int* __restrict__ part,
                                                  int* __restrict__ rp, int* __restrict__ gcur, int n){
  __shared__ int s[256];
  int b=blockIdx.x, t=threadIdx.x;
  int chunk=(n+SCB-1)/SCB;
  int lo=b*chunk, hi=min(lo+chunk,n);
  int tchunk=(chunk+255)/256;
  int tlo=lo+t*tchunk, thi=min(tlo+tchunk,hi);
  int acc=0;
  for(int i=tlo;i<thi;i++) acc+=deg[i];
  s[t]=acc; __syncthreads();
  for(int off=1;off<256;off<<=1){
    int v=(t>=off)? s[t-off]:0;
    __syncthreads();
    s[t]+=v;
    __syncthreads();
  }
  int pre=part[b]+((t>0)? s[t-1]:0);
  for(int i=tlo;i<thi;i++){
    rp[i]=pre;
    if((i&(RNG-1))==0) gcur[(i>>7)*32]=pre;
    pre+=deg[i];
  }
  if(b==SCB-1 && t==0) rp[n]=part[b]+s[255];
}

// ======================= bucketed CSR fill =======================
__global__ __launch_bounds__(256) void k_binscat(const int* __restrict__ row, const int* __restrict__ col,
                       int* __restrict__ gcur, unsigned* __restrict__ tmp, int E, int nbuck){
  __shared__ int lcnt[NBUCKMAX];
  __shared__ int lcur[NBUCKMAX];
  int t=threadIdx.x;
  for(int i=t;i<nbuck;i+=256) lcnt[i]=0;
  __syncthreads();
  int lo=blockIdx.x*CH1, hi=min(lo+CH1,E);
  for(int i=lo+t;i<hi;i+=256) atomicAdd(&lcnt[col[i]>>7],1);
  __syncthreads();
  for(int i=t;i<nbuck;i+=256){
    int cnt=lcnt[i];
    lcur[i]=(cnt>0)? atomicAdd(&gcur[i*32],cnt):0;
  }
  __syncthreads();
  for(int i=lo+t;i<hi;i+=256){
    int c=col[i], r=row[i];
    int pos=atomicAdd(&lcur[c>>7],1);
    tmp[pos]=((unsigned)r<<7)|(unsigned)(c&127);
  }
}

__global__ __launch_bounds__(256) void k_place(const unsigned* __restrict__ tmp, const int* __restrict__ rp,
                      const float* __restrict__ dinv, int2* __restrict__ epack, int n, int nbuck){
  __shared__ int lfill[RNG];
  __shared__ int lrp[RNG];
  __shared__ float ldv[RNG];
  int b=blockIdx.x, t=threadIdx.x;
  int nbase=b*RNG;
  int nn=min(RNG,n-nbase);
  if(t<nn){ lfill[t]=0; lrp[t]=rp[nbase+t]; ldv[t]=dinv[nbase+t]; }
  __syncthreads();
  int lo=rp[nbase], hi=rp[min(nbase+RNG,n)];
  for(int j=lo+t;j<hi;j+=256){
    unsigned v=tmp[j];
    int cl=v&127;
    int r=(int)(v>>7);
    int pos=atomicAdd(&lfill[cl],1);
    epack[lrp[cl]+pos]=make_int2(r,__float_as_int(dinv[r]*ldv[cl]));
  }
}

// ======================= MFMA B-fragment prep =======================
// mfma_f32_16x16x32_bf16 fragments:
//   A: lane l holds row (l&15), k = s*32 + (l>>4)*8 + r   (r=0..7)
//   B: lane l holds col (l&15), k = s*32 + (l>>4)*8 + r
//   D: lane l holds col (l&15), row = (l>>4)*4 + reg
// Plain (t-major) frags: Bf[((t*S + s)*64 + lane)*8 + r] = W[k][c], t=c/16, S=K/32.
__global__ void k_prep_plain(const float* __restrict__ W, unsigned short* __restrict__ Bf, int K, int C){
  int i=blockIdx.x*blockDim.x+threadIdx.x;
  if(i>=K*C) return;
  int k=i/C, c=i%C;
  int t=c>>4, s=k>>5, lane=(c&15)|(((k>>3)&3)<<4), r=k&7;
  int S=K>>5;
  Bf[(((t*S)+s)*64+lane)*8+r]=f2bf(W[(size_t)k*C+c]);
}

// Assembled GRU weights, S-MAJOR frag order (f = s*16+t) so each 16KB quarter (one s) is contiguous.
// X=[m|h] (K=128), cols: [0,64)=r, [64,128)=z, [128,192)=in_, [192,256)=hn.
__global__ void k_prep_gru(const float* __restrict__ wih, const float* __restrict__ whh,
                           unsigned short* __restrict__ Bf){
  int i=blockIdx.x*blockDim.x+threadIdx.x;
  if(i>=128*256) return;
  int k=i>>8, c=i&255;
  float v;
  if(c<128){          // r,z
    v = (k<64) ? wih[c*64+k] : whh[c*64+(k-64)];
  } else if(c<192){   // in_
    v = (k<64) ? wih[c*64+k] : 0.f;
  } else {            // hn
    v = (k<64) ? 0.f : whh[(c-64)*64+(k-64)];
  }
  int t=c>>4, s=k>>5, lane=(c&15)|(((k>>3)&3)<<4), r=k&7;
  Bf[(((s*16)+t)*64+lane)*8+r]=f2bf(v);
}

// ======================= lin0: hb = bf16(relu(x @ W + b)), LDS-staged coalesced store ===================
__global__ __launch_bounds__(256) void k_lin0(const float* __restrict__ x, const unsigned short* __restrict__ Bf,
                      const float* __restrict__ bias,
                      unsigned short* __restrict__ hb, int ngrp){
  __shared__ __align__(16) unsigned short lt[4][16][72];
  int l=threadIdx.x&63, w=threadIdx.x>>6;
  int g=blockIdx.x*4+w;
  if(g>=ngrp) return;
  int row16=l&15, koff=(l>>4)*8, l16=l&15;
  f32x4 acc[4]={};
  const float* xr = x + (size_t)(g*16+row16)*128 + koff;
  #pragma unroll
  for(int s=0;s<4;s++){
    f32x4 a0=*(const f32x4*)(xr+s*32);
    f32x4 a1=*(const f32x4*)(xr+s*32+4);
    bf16x8 af;
    #pragma unroll
    for(int r=0;r<4;r++){ af[r]=(short)f2bf(a0[r]); af[4+r]=(short)f2bf(a1[r]); }
    #pragma unroll
    for(int t=0;t<4;t++){
      bf16x8 bf=*(const bf16x8*)(Bf+(((t*4)+s)*64+l)*8);
      acc[t]=__builtin_amdgcn_mfma_f32_16x16x32_bf16(af,bf,acc[t],0,0,0);
    }
  }
  #pragma unroll
  for(int t=0;t<4;t++){
    int c=t*16+l16;
    float b=bias[c];
    #pragma unroll
    for(int j=0;j<4;j++)
      lt[w][(l>>4)*4+j][c]=f2bf(fmaxf(acc[t][j]+b,0.f));
  }
  #pragma unroll
  for(int i=0;i<4;i++){
    int rl=i*4+(l>>4);
    uint2 v=*(const uint2*)&lt[w][rl][l16*4];
    ((uint2*)hb)[(((unsigned)(g*16+rl))<<4)+l16]=v;
  }
}

// ======================= fused aggregate + conv + GRU (round-13 configuration) ===========
__global__ __launch_bounds__(256,4) void k_gruagg(
                     const unsigned short* __restrict__ hin, unsigned short* __restrict__ hout,
                     const int* __restrict__ rp, const int2* __restrict__ epack,
                     const float* __restrict__ dinv,
                     const unsigned short* __restrict__ Bcnv, const float* __restrict__ cb,
                     const unsigned short* __restrict__ Bgru,
                     const float* __restrict__ bih, const float* __restrict__ bhh,
                     float* __restrict__ h, int last, int ngrp, int n){
  __shared__ __align__(16) unsigned short Bs[8192];          // 16 KB: one s-quarter of Bgru
  __shared__ __align__(16) unsigned short tAH[4][2][16][72]; // [w][0]=agg/m tile, [w][1]=h tile
  int tid=threadIdx.x;
  int l=tid&63, w=tid>>6;
  int g=blockIdx.x*4+w;
  bool act = g<ngrp;
  int gc = act? g : (ngrp-1);
  int q=l>>4, l16=l&15;
  int row16=l&15, koff=(l>>4)*8;

  unsigned short (*tA)[72] = tAH[w][0];
  unsigned short (*tH)[72] = tAH[w][1];

  // conv B-frags into registers (issued early, resolve under gather)
  bf16x8 bc[8];
  #pragma unroll
  for(int f=0;f<8;f++) bc[f]=*(const bf16x8*)(Bcnv+((size_t)f*64+l)*8);

  // stage Bgru quarter s=0
  {
    const f32x4* gh=(const f32x4*)Bgru; f32x4* lh=(f32x4*)Bs;
    #pragma unroll
    for(int i=0;i<4;i++) lh[i*256+tid]=gh[i*256+tid];
  }

  // ---- gather: 4 rounds; quarter q owns node gc*16+rr*4+q; 8-wide main, 4/2/1 tails ----
  const uint2* h64=(const uint2*)hin;
  #pragma unroll
  for(int rr=0;rr<4;rr++){
    int node=min(gc*16+rr*4+q, n-1);
    float a0=0.f,a1=0.f,a2=0.f,a3=0.f, b0=0.f,b1=0.f,b2=0.f,b3=0.f;
    int s=rp[node], e=rp[node+1];
    uint2 selfp=h64[((unsigned)node<<4)+l16];
    int j=s;
    for(; j+7<e; j+=8){
      int2 e0=epack[j],   e1=epack[j+1], e2=epack[j+2], e3=epack[j+3];
      int2 e4=epack[j+4], e5=epack[j+5], e6=epack[j+6], e7=epack[j+7];
      uint2 p0=h64[((unsigned)e0.x<<4)+l16];
      uint2 p1=h64[((unsigned)e1.x<<4)+l16];
      uint2 p2=h64[((unsigned)e2.x<<4)+l16];
      uint2 p3=h64[((unsigned)e3.x<<4)+l16];
      uint2 p4=h64[((unsigned)e4.x<<4)+l16];
      uint2 p5=h64[((unsigned)e5.x<<4)+l16];
      uint2 p6=h64[((unsigned)e6.x<<4)+l16];
      uint2 p7=h64[((unsigned)e7.x<<4)+l16];
      float n0=__int_as_float(e0.y), n1=__int_as_float(e1.y);
      float n2=__int_as_float(e2.y), n3=__int_as_float(e3.y);
      float n4=__int_as_float(e4.y), n5=__int_as_float(e5.y);
      float n6=__int_as_float(e6.y), n7=__int_as_float(e7.y);
      a0+=n0*bf2f((unsigned short)p0.x); a1+=n0*bf2f((unsigned short)(p0.x>>16));
      a2+=n0*bf2f((unsigned short)p0.y); a3+=n0*bf2f((unsigned short)(p0.y>>16));
      b0+=n1*bf2f((unsigned short)p1.x); b1+=n1*bf2f((unsigned short)(p1.x>>16));
      b2+=n1*bf2f((unsigned short)p1.y); b3+=n1*bf2f((unsigned short)(p1.y>>16));
      a0+=n2*bf2f((unsigned short)p2.x); a1+=n2*bf2f((unsigned short)(p2.x>>16));
      a2+=n2*bf2f((unsigned short)p2.y); a3+=n2*bf2f((unsigned short)(p2.y>>16));
      b0+=n3*bf2f((unsigned short)p3.x); b1+=n3*bf2f((unsigned short)(p3.x>>16));
      b2+=n3*bf2f((unsigned short)p3.y); b3+=n3*bf2f((unsigned short)(p3.y>>16));
      a0+=n4*bf2f((unsigned short)p4.x); a1+=n4*bf2f((unsigned short)(p4.x>>16));
      a2+=n4*bf2f((unsigned short)p4.y); a3+=n4*bf2f((unsigned short)(p4.y>>16));
      b0+=n5*bf2f((unsigned short)p5.x); b1+=n5*bf2f((unsigned short)(p5.x>>16));
      b2+=n5*bf2f((unsigned short)p5.y); b3+=n5*bf2f((unsigned short)(p5.y>>16));
      a0+=n6*bf2f((unsigned short)p6.x); a1+=n6*bf2f((unsigned short)(p6.x>>16));
      a2+=n6*bf2f((unsigned short)p6.y); a3+=n6*bf2f((unsigned short)(p6.y>>16));
      b0+=n7*bf2f((unsigned short)p7.x); b1+=n7*bf2f((unsigned short)(p7.x>>16));
      b2+=n7*bf2f((unsigned short)p7.y); b3+=n7*bf2f((unsigned short)(p7.y>>16));
    }
    for(; j+3<e; j+=4){
      int2 e0=epack[j];
      int2 e1=epack[j+1];
      int2 e2=epack[j+2];
      int2 e3=epack[j+3];
      uint2 p0=h64[((unsigned)e0.x<<4)+l16];
      uint2 p1=h64[((unsigned)e1.x<<4)+l16];
      uint2 p2=h64[((unsigned)e2.x<<4)+l16];
      uint2 p3=h64[((unsigned)e3.x<<4)+l16];
      float n0=__int_as_float(e0.y), n1=__int_as_float(e1.y);
      float n2=__int_as_float(e2.y), n3=__int_as_float(e3.y);
      a0+=n0*bf2f((unsigned short)p0.x); a1+=n0*bf2f((unsigned short)(p0.x>>16));
      a2+=n0*bf2f((unsigned short)p0.y); a3+=n0*bf2f((unsigned short)(p0.y>>16));
      b0+=n1*bf2f((unsigned short)p1.x); b1+=n1*bf2f((unsigned short)(p1.x>>16));
      b2+=n1*bf2f((unsigned short)p1.y); b3+=n1*bf2f((unsigned short)(p1.y>>16));
      a0+=n2*bf2f((unsigned short)p2.x); a1+=n2*bf2f((unsigned short)(p2.x>>16));
      a2+=n2*bf2f((unsigned short)p2.y); a3+=n2*bf2f((unsigned short)(p2.y>>16));
      b0+=n3*bf2f((unsigned short)p3.x); b1+=n3*bf2f((unsigned short)(p3.x>>16));
      b2+=n3*bf2f((unsigned short)p3.y); b3+=n3*bf2f((unsigned short)(p3.y>>16));
    }
    for(; j+1<e; j+=2){
      int2 e0=epack[j];
      int2 e1=epack[j+1];
      uint2 p0=h64[((unsigned)e0.x<<4)+l16];
      uint2 p1=h64[((unsigned)e1.x<<4)+l16];
      float n0=__int_as_float(e0.y), n1=__int_as_float(e1.y);
      a0+=n0*bf2f((unsigned short)p0.x); a1+=n0*bf2f((unsigned short)(p0.x>>16));
      a2+=n0*bf2f((unsigned short)p0.y); a3+=n0*bf2f((unsigned short)(p0.y>>16));
      b0+=n1*bf2f((unsigned short)p1.x); b1+=n1*bf2f((unsigned short)(p1.x>>16));
      b2+=n1*bf2f((unsigned short)p1.y); b3+=n1*bf2f((unsigned short)(p1.y>>16));
    }
    if(j<e){
      int2 e0=epack[j];
      uint2 p0=h64[((unsigned)e0.x<<4)+l16];
      float n0=__int_as_float(e0.y);
      a0+=n0*bf2f((unsigned short)p0.x); a1+=n0*bf2f((unsigned short)(p0.x>>16));
      a2+=n0*bf2f((unsigned short)p0.y); a3+=n0*bf2f((unsigned short)(p0.y>>16));
    }
    float dv=dinv[node]; dv*=dv;
    a0+=b0+dv*bf2f((unsigned short)selfp.x);
    a1+=b1+dv*bf2f((unsigned short)(selfp.x>>16));
    a2+=b2+dv*bf2f((unsigned short)selfp.y);
    a3+=b3+dv*bf2f((unsigned short)(selfp.y>>16));
    int ri=rr*4+q;
    unsigned* tAp=(unsigned*)&tA[ri][l16*4];
    tAp[0]=(unsigned)f2bf(a0)|(((unsigned)f2bf(a1))<<16);
    tAp[1]=(unsigned)f2bf(a2)|(((unsigned)f2bf(a3))<<16);
    unsigned* tHp=(unsigned*)&tH[ri][l16*4];
    tHp[0]=selfp.x; tHp[1]=selfp.y;
  }

  // ---- conv mini-GEMM: m = relu(agg[16x64] @ Wc + cb); A-frags from tA (same wave) ----
  f32x4 accm[4]={};
  #pragma unroll
  for(int s=0;s<2;s++){
    bf16x8 af=*(const bf16x8*)&tA[row16][s*32+koff];
    #pragma unroll
    for(int t=0;t<4;t++)
      accm[t]=__builtin_amdgcn_mfma_f32_16x16x32_bf16(af,bc[t*2+s],accm[t],0,0,0);
  }
  // m -> tA (overwrite; same-wave lockstep safe)
  #pragma unroll
  for(int t=0;t<4;t++){
    int c=t*16+l16;
    float b=cb[c];
    #pragma unroll
    for(int j=0;j<4;j++)
      tA[(l>>4)*4+j][c]=f2bf(fmaxf(accm[t][j]+b,0.f));
  }

  // ---- GRU GEMM over 4 K-slices, Bs restaged per slice ----
  f32x4 acc[16]={};
  __syncthreads();   // Bs quarter 0 visible
  #pragma unroll
  for(int s=0;s<4;s++){
    if(s>0){
      __syncthreads();  // prior quarter reads done
      const f32x4* gh=(const f32x4*)(Bgru+(size_t)s*8192); f32x4* lh=(f32x4*)Bs;
      #pragma unroll
      for(int i=0;i<4;i++) lh[i*256+tid]=gh[i*256+tid];
      __syncthreads();  // quarter s visible
    }
    bf16x8 af;
    if(s<2) af=*(const bf16x8*)&tA[row16][s*32+koff];
    else    af=*(const bf16x8*)&tH[row16][(s-2)*32+koff];
    #pragma unroll
    for(int t=0;t<16;t++){
      bf16x8 bf=*(const bf16x8*)(Bs+((size_t)t*64+l)*8);
      acc[t]=__builtin_amdgcn_mfma_f32_16x16x32_bf16(af,bf,acc[t],0,0,0);
    }
  }

  if(!act) return;
  // ---- epilogue: gates in-register; hold from tH (read before overwrite) ----
  float hn[16];
  #pragma unroll
  for(int t=0;t<4;t++){
    int d=t*16+l16;
    float br =bih[d]    +bhh[d];
    float bz =bih[64+d] +bhh[64+d];
    float bni=bih[128+d];
    float bnh=bhh[128+d];
    #pragma unroll
    for(int j=0;j<4;j++){
      float r  = sigmoidf_(acc[t][j]   + br);
      float z  = sigmoidf_(acc[4+t][j] + bz);
      float nc = tanhf_(acc[8+t][j] + bni + r*(acc[12+t][j] + bnh));
      float hold=bf2f(tH[(l>>4)*4+j][d]);
      hn[t*4+j]=(1.f-z)*nc + z*hold;
    }
  }
  // stage hn (bf16) into tH, then coalesced uint2 writeback (wave-lockstep: all hold reads precede)
  #pragma unroll
  for(int t=0;t<4;t++){
    int d=t*16+l16;
    #pragma unroll
    for(int j=0;j<4;j++)
      tH[(l>>4)*4+j][d]=f2bf(hn[t*4+j]);
  }
  #pragma unroll
  for(int i=0;i<4;i++){
    int rl=i*4+(l>>4);
    uint2 v=*(const uint2*)&tH[rl][l16*4];
    ((uint2*)hout)[(((unsigned)(gc*16+rl))<<4)+l16]=v;
  }
  if(last){
    // f32 feat via LDS transpose over the (now-free) tA+tH storage: float[16][68], 4352B <= 4608B
    float* ft=(float*)&tAH[w][0][0][0];
    #pragma unroll
    for(int t=0;t<4;t++){
      int d=t*16+l16;
      #pragma unroll
      for(int j=0;j<4;j++)
        ft[((l>>4)*4+j)*68+d]=hn[t*4+j];
    }
    #pragma unroll
    for(int i=0;i<4;i++){
      int rl=i*4+(l>>4);
      f32x4 v=*(const f32x4*)&ft[rl*68+l16*4];
      *(f32x4*)&h[(size_t)(gc*16+rl)*64+l16*4]=v;
    }
  }
}

// ======================= Set2Set: parallel attention partials =======================
__global__ __launch_bounds__(256) void k_attn_part(const unsigned short* __restrict__ hb, const int* __restrict__ batch,
                        const float* __restrict__ hl, float* __restrict__ apart, int n){
  int b=blockIdx.x/KB, kb=blockIdx.x%KB;
  int tid=threadIdx.x, lane=tid&63, w=tid>>6;
  __shared__ float qs[64];
  __shared__ float wm[4], wsm[4];
  __shared__ float wacc[4][64];
  if(tid<64) qs[tid]=hl[b*64+tid];
  int lo=lower_bound_i(batch,n,b), hi=lower_bound_i(batch,n,b+1);
  int cnt=hi-lo;
  int chunk=(cnt+KB-1)/KB;
  int slo=lo+kb*chunk, shi=min(slo+chunk,hi);
  __syncthreads();
  float q=qs[lane];
  float mw=-3.0e38f, sw=0.f, aw=0.f;
  for(int i=slo+w;i<shi;i+=4){
    float f=bf2f(hb[(size_t)i*64+lane]);
    float v=f*q;
    #pragma unroll
    for(int off=32;off;off>>=1) v+=__shfl_xor(v,off);
    if(v>mw){
      float sc=__expf(mw-v);
      sw=sw*sc+1.f;
      aw=aw*sc+f;
      mw=v;
    } else {
      float p=__expf(v-mw);
      sw+=p;
      aw+=p*f;
    }
  }
  if(lane==0){ wm[w]=mw; wsm[w]=sw; }
  wacc[w][lane]=aw;
  __syncthreads();
  if(w==0){
    float M=fmaxf(fmaxf(wm[0],wm[1]),fmaxf(wm[2],wm[3]));
    float S=0.f, A=0.f;
    #pragma unroll
    for(int k=0;k<4;k++){
      float sc=__expf(wm[k]-M);
      S+=wsm[k]*sc;
      A+=wacc[k][lane]*sc;
    }
    float* p=apart+(size_t)blockIdx.x*68;
    p[lane]=A;
    if(lane==0){ p[64]=M; p[65]=S; }
  }
}

// merge partials -> r_read (qstar[64:128]); optionally run next LSTM cell
__global__ __launch_bounds__(256) void k_merge_lstm(const float* __restrict__ apart,
                   float* __restrict__ qstar, float* __restrict__ hl, float* __restrict__ cl,
                   const float* __restrict__ wih, const float* __restrict__ whh,
                   const float* __restrict__ bih, const float* __restrict__ bhh,
                   int do_merge, int do_lstm){
  int b=blockIdx.x, tid=threadIdx.x;
  __shared__ float qs[128];
  __shared__ float gates[256];
  if(do_merge){
    if(tid<64){
      const float* p0=apart+(size_t)b*KB*68;
      float M=-3.0e38f;
      #pragma unroll
      for(int k=0;k<KB;k++) M=fmaxf(M,p0[k*68+64]);
      float S=0.f, A=0.f;
      #pragma unroll
      for(int k=0;k<KB;k++){
        float sc=__expf(p0[k*68+64]-M);
        S+=p0[k*68+65]*sc;
        A+=p0[k*68+tid]*sc;
      }
      float inv=(S>0.f)? 1.f/S:0.f;
      float r=A*inv;
      qs[64+tid]=r;
      qstar[b*128+64+tid]=r;
    }
  } else {
    if(tid<64) qs[64+tid]=qstar[b*128+64+tid];
  }
  if(tid<64) qs[tid]=hl[b*64+tid];   // q_t == previous LSTM hidden
  __syncthreads();
  if(!do_lstm) return;
  float acc=bih[tid]+bhh[tid];
  const float* wi=wih+(size_t)tid*128;
  #pragma unroll 8
  for(int k=0;k<128;k++) acc+=qs[k]*wi[k];
  const float* w2=whh+(size_t)tid*64;
  #pragma unroll 8
  for(int k=0;k<64;k++) acc+=qs[k]*w2[k];
  gates[tid]=acc;
  __syncthreads();
  if(tid<64){
    float i_=gates[tid], f_=gates[64+tid], g_=gates[128+tid], o_=gates[192+tid];
    float c=sigmoidf_(f_)*cl[b*64+tid]+sigmoidf_(i_)*tanhf(g_);
    float hn=sigmoidf_(o_)*tanhf(c);
    cl[b*64+tid]=c; hl[b*64+tid]=hn;
    qstar[b*128+tid]=hn;
  }
}

extern "C" void kernel_launch(void* const* d_in, const int* in_sizes, int n_in,
                              void* d_out, int out_size, void* d_ws, size_t ws_size,
                              hipStream_t stream){
  const float* x      =(const float*)d_in[0];
  const int*   ei     =(const int*)d_in[1];
  const int*   batch  =(const int*)d_in[2];
  const float* lin0_w =(const float*)d_in[3];
  const float* lin0_b =(const float*)d_in[4];
  const float* conv_w =(const float*)d_in[5];
  const float* conv_b =(const float*)d_in[6];
  const float* gwih   =(const float*)d_in[7];
  const float* gwhh   =(const float*)d_in[8];
  const float* gbih   =(const float*)d_in[9];
  const float* gbhh   =(const float*)d_in[10];
  const float* lwih   =(const float*)d_in[11];
  const float* lwhh   =(const float*)d_in[12];
  const float* lbih   =(const float*)d_in[13];
  const float* lbhh   =(const float*)d_in[14];

  int N = in_sizes[0]/FEATD;
  int E = in_sizes[1]/2;
  const int* row = ei;
  const int* col = ei + E;

  float* qstar = (float*)d_out;            // [256,128]
  float* h     = (float*)d_out + NB*2*DIM; // [N,64] 'feat' = f32 h (written by last k_gruagg)

  char* ws=(char*)d_ws;
  size_t off=0;
  auto alloc=[&](size_t bytes)->void*{ void* p=ws+off; off=(off+bytes+255)&~(size_t)255; return p; };
  int*   deg  =(int*)  alloc((size_t)N*4);
  float* dinv =(float*)alloc((size_t)N*4);
  int*   rp   =(int*)  alloc((size_t)(N+1)*4);
  int*   part =(int*)  alloc((size_t)SCB*4);
  int*   gcur =(int*)  alloc((size_t)NBUCKMAX*32*4);
  unsigned* tmp=(unsigned*)alloc((size_t)E*4);
  int2*  epack=(int2*) alloc((size_t)E*8);
  unsigned short* hb0  =(unsigned short*)alloc((size_t)N*64*2);
  unsigned short* hb1  =(unsigned short*)alloc((size_t)N*64*2);
  float* hl   =(float*)alloc((size_t)NB*DIM*4);
  float* cl   =(float*)alloc((size_t)NB*DIM*4);
  float* apart=(float*)alloc((size_t)NB*KB*68*4);
  unsigned short* Bgru =(unsigned short*)alloc(128*256*2);
  unsigned short* Blin =(unsigned short*)alloc(128*64*2);
  unsigned short* Bcnv =(unsigned short*)alloc(64*64*2);

  hipMemsetAsync(deg ,0,(size_t)N*4,stream);
  hipMemsetAsync(hl  ,0,(size_t)NB*DIM*4,stream);
  hipMemsetAsync(cl  ,0,(size_t)NB*DIM*4,stream);
  hipMemsetAsync(qstar,0,(size_t)NB*2*DIM*4,stream);

  int nbuck=(N+RNG-1)/RNG;

  k_count<<<(E+255)/256,256,0,stream>>>(col,deg,E);
  k_scan_part<<<SCB,256,0,stream>>>(deg,part,dinv,N);
  k_scan_mid <<<1,256,0,stream>>>(part);
  k_scan_out <<<SCB,256,0,stream>>>(deg,part,rp,gcur,N);
  k_binscat<<<(E+CH1-1)/CH1,256,0,stream>>>(row,col,gcur,tmp,E,nbuck);
  k_place<<<nbuck,256,0,stream>>>(tmp,rp,dinv,epack,N,nbuck);

  k_prep_plain<<<(128*64+255)/256,256,0,stream>>>(lin0_w,Blin,128,64);
  k_prep_plain<<<(64*64+255)/256,256,0,stream>>>(conv_w,Bcnv,64,64);
  k_prep_gru  <<<(128*256+255)/256,256,0,stream>>>(gwih,gwhh,Bgru);

  int ngrp=(N+15)/16;
  int gb=(ngrp+3)/4;

  k_lin0<<<gb,256,0,stream>>>(x,Blin,lin0_b,hb0,ngrp);

  // h double-buffer: it0 hb0->hb1, it1 hb1->hb0, it2 hb0->hb1 (final in hb1)
  k_gruagg<<<gb,256,0,stream>>>(hb0,hb1,rp,epack,dinv,Bcnv,conv_b,Bgru,gbih,gbhh,h,0,ngrp,N);
  k_gruagg<<<gb,256,0,stream>>>(hb1,hb0,rp,epack,dinv,Bcnv,conv_b,Bgru,gbih,gbhh,h,0,ngrp,N);
  k_gruagg<<<gb,256,0,stream>>>(hb0,hb1,rp,epack,dinv,Bcnv,conv_b,Bgru,gbih,gbhh,h,1,ngrp,N);

  // Set2Set: lstm0; [attn, merge+lstm] x2; attn; merge(final)
  k_merge_lstm<<<NB,256,0,stream>>>(apart,qstar,hl,cl,lwih,lwhh,lbih,lbhh,0,1);
  for(int st=0;st<3;st++){
    k_attn_part<<<NB*KB,256,0,stream>>>(hb1,batch,hl,apart,N);
    int do_lstm = (st<2)? 1:0;
    k_merge_lstm<<<NB,256,0,stream>>>(apart,qstar,hl,cl,lwih,lwhh,lbih,lbhh,1,do_lstm);
  }
}